// Round 8
// baseline (470.010 us; speedup 1.0000x reference)
//
#include <hip/hip_runtime.h>

#define TPB 512
#define P_BLK 16        // parents per block, 1 per 32-thread group

__device__ __forceinline__ float bf_lo(unsigned int u) { return __uint_as_float(u << 16); }
__device__ __forceinline__ float bf_hi(unsigned int u) { return __uint_as_float(u & 0xffff0000u); }
__device__ __forceinline__ unsigned int bf_rne(float f) {   // f32 -> bf16 bits (RNE)
    unsigned int u = __float_as_uint(f);
    u += 0x7fffu + ((u >> 16) & 1u);
    return u >> 16;
}
__device__ __forceinline__ unsigned int pack2(float a, float b) {
    return bf_rne(a) | (bf_rne(b) << 16);
}

__global__ __launch_bounds__(TPB) void equi_unpool_v8(
    const float* __restrict__ x_mv,    // [Np,32,16]
    const float* __restrict__ x_s,     // [Np,64]
    const float* __restrict__ skip_mv, // [Nc,32,16]
    const float* __restrict__ skip_s,  // [Nc,64]
    const float* __restrict__ w_mv,    // [32,32,9]
    const float* __restrict__ w_s2mv,  // [32,64]
    const float* __restrict__ w_mv2s,  // [64,32]
    const float* __restrict__ w_s2s,   // [64,64]
    const float* __restrict__ b_s,     // [64]
    float* __restrict__ out_mv,        // [Nc,32,16]
    float* __restrict__ out_s,         // [Nc,64]
    int n_parent, int stride)
{
    // All weights bf16 in LDS; 37.1 KB total -> 4 blocks/CU x 8 waves = 32 waves/CU.
    // lw row [i][o][6xu32]: slots 0-8 = w_mv[o][i][*], 9/10 = w_mv2s[o][i]/[o+32][i].
    //   read as 3x ds_read_b64, lane-stride 24B -> 2-way aliasing (free, m136).
    // l2s  [spp][ch] uint2: (w_s2s[ch][4spp],[+1] | [+2],[+3]) -> b64, 2-way.
    // l2mv [spp][o]  uint2: same packing of w_s2mv.
    __shared__ unsigned int lw[6144];   // 24 KB
    __shared__ uint2 l2s[1024];         //  8 KB
    __shared__ uint2 l2mv[512];         //  4 KB
    __shared__ float lbs[64];           // 256 B

    const int tid = threadIdx.x;
    const int p0 = blockIdx.x * P_BLK;

    // ---- stage main-loop weights (dst-linear => conflict-free ds_write) ----
    #pragma unroll
    for (int base = 0; base < 6144; base += TPB) {
        int dst = base + tid;
        int t = dst / 6;                       // row = (i,o)
        int k = dst - t * 6;                   // u32 slot: bf16 idx 2k, 2k+1
        int oo = t & 31, ii = t >> 5;
        float v0 = 0.f, v1 = 0.f;
        int s0i = 2 * k, s1i = 2 * k + 1;
        if (s0i < 9)        v0 = w_mv[oo * 288 + ii * 9 + s0i];
        else if (s0i == 9)  v0 = w_mv2s[oo * 32 + ii];
        else if (s0i == 10) v0 = w_mv2s[(oo + 32) * 32 + ii];
        if (s1i < 9)        v1 = w_mv[oo * 288 + ii * 9 + s1i];
        else if (s1i == 9)  v1 = w_mv2s[oo * 32 + ii];
        else if (s1i == 10) v1 = w_mv2s[(oo + 32) * 32 + ii];
        lw[dst] = bf_rne(v0) | (bf_rne(v1) << 16);
    }
    // ---- stage transposed scalar-path weights ----
    #pragma unroll
    for (int base = 0; base < 2048; base += TPB) {
        int dst = base + tid;                  // u32 index into l2s
        int spp = dst >> 7;                    // 128 u32 per spp row
        int r = dst & 127;
        int ch = r >> 1, half = r & 1;
        int sb = 4 * spp + 2 * half;
        ((unsigned int*)l2s)[dst] = pack2(w_s2s[ch * 64 + sb], w_s2s[ch * 64 + sb + 1]);
    }
    {
        int dst = tid;                         // 1024 u32 into l2mv (TPB=512: 2 rounds)
        #pragma unroll
        for (int rou = 0; rou < 2; ++rou, dst += TPB) {
            int spp = dst >> 6;
            int r = dst & 63;
            int o_ = r >> 1, half = r & 1;
            int sb = 4 * spp + 2 * half;
            ((unsigned int*)l2mv)[dst] = pack2(w_s2mv[o_ * 64 + sb], w_s2mv[o_ * 64 + sb + 1]);
        }
    }
    if (tid < 64) lbs[tid] = b_s[tid];
    __syncthreads();   // ONE barrier; everything below is barrier-free

    const int o  = tid & 31;                   // output channel
    const int pl = tid >> 5;                   // local parent
    const int p  = p0 + pl;
    if (p >= n_parent) return;

    float a[16];
    #pragma unroll
    for (int j = 0; j < 16; ++j) a[j] = 0.f;
    float s0 = 0.f, s1 = 0.f;

    // ---- main loop: x direct from global (broadcast float4, L2/L3-served; TLP hides) ----
    const float4* xg = (const float4*)(x_mv + (size_t)p * 512);
    #pragma unroll 4
    for (int i = 0; i < 32; ++i) {
        float4 X0 = xg[i * 4 + 0];
        float4 X1 = xg[i * 4 + 1];
        float4 X2 = xg[i * 4 + 2];
        float4 X3 = xg[i * 4 + 3];
        const unsigned int* wp = &lw[(i * 32 + o) * 6];
        uint2 q0 = *(const uint2*)(wp + 0);
        uint2 q1 = *(const uint2*)(wp + 2);
        uint2 q2 = *(const uint2*)(wp + 4);
        float w0 = bf_lo(q0.x), w1 = bf_hi(q0.x);
        float w2 = bf_lo(q0.y), w3 = bf_hi(q0.y);
        float w4 = bf_lo(q1.x), w5 = bf_hi(q1.x);
        float w6 = bf_lo(q1.y), w7 = bf_hi(q1.y);
        float w8 = bf_lo(q2.x), wm0 = bf_hi(q2.x);
        float wm1 = bf_lo(q2.y);

        a[0]  += X0.x * w0;
        a[1]  += X0.y * w1 + X0.x * w5;
        a[2]  += X0.z * w1;
        a[3]  += X0.w * w1;
        a[4]  += X1.x * w1;
        a[5]  += X1.y * w2 + X0.z * w6;
        a[6]  += X1.z * w2 + X0.w * w6;
        a[7]  += X1.w * w2 + X1.x * w6;
        a[8]  += X2.x * w2;
        a[9]  += X2.y * w2;
        a[10] += X2.z * w2;
        a[11] += X2.w * w3 + X2.x * w7;
        a[12] += X3.x * w3 + X2.y * w7;
        a[13] += X3.y * w3 + X2.z * w7;
        a[14] += X3.z * w3;
        a[15] += X3.w * w4 + X3.z * w8;
        s0 += X0.x * wm0;
        s1 += X0.x * wm1;
    }

    // ---- scalar inputs: s2mv (into a[0]) and s2s via transposed LDS (no TA gather) ----
    const float4* xsv = (const float4*)(x_s + (size_t)p * 64);
    #pragma unroll 4
    for (int spp = 0; spp < 16; ++spp) {
        float4 xv = xsv[spp];
        uint2 m  = l2mv[spp * 32 + o];
        uint2 wa = l2s[spp * 64 + o];
        uint2 wb = l2s[spp * 64 + o + 32];
        a[0] += xv.x * bf_lo(m.x) + xv.y * bf_hi(m.x) + xv.z * bf_lo(m.y) + xv.w * bf_hi(m.y);
        s0   += xv.x * bf_lo(wa.x) + xv.y * bf_hi(wa.x) + xv.z * bf_lo(wa.y) + xv.w * bf_hi(wa.y);
        s1   += xv.x * bf_lo(wb.x) + xv.y * bf_hi(wb.x) + xv.z * bf_lo(wb.y) + xv.w * bf_hi(wb.y);
    }
    s0 += lbs[o];
    s1 += lbs[o + 32];

    // ---- epilogue: broadcast to children, add skip, store (coalesced float4) ----
    for (int r = 0; r < stride; ++r) {
        size_t c = (size_t)p * stride + r;
        const float4* sk = (const float4*)(skip_mv + c * 512 + o * 16);
        float4* om = (float4*)(out_mv + c * 512 + o * 16);
        float4 k0 = sk[0], k1 = sk[1], k2 = sk[2], k3 = sk[3];
        om[0] = make_float4(k0.x + a[0],  k0.y + a[1],  k0.z + a[2],  k0.w + a[3]);
        om[1] = make_float4(k1.x + a[4],  k1.y + a[5],  k1.z + a[6],  k1.w + a[7]);
        om[2] = make_float4(k2.x + a[8],  k2.y + a[9],  k2.z + a[10], k2.w + a[11]);
        om[3] = make_float4(k3.x + a[12], k3.y + a[13], k3.z + a[14], k3.w + a[15]);
        out_s[c * 64 + o]      = skip_s[c * 64 + o] + s0;
        out_s[c * 64 + o + 32] = skip_s[c * 64 + o + 32] + s1;
    }
}

extern "C" void kernel_launch(void* const* d_in, const int* in_sizes, int n_in,
                              void* d_out, int out_size, void* d_ws, size_t ws_size,
                              hipStream_t stream) {
    const float* x_mv    = (const float*)d_in[0];
    const float* x_s     = (const float*)d_in[1];
    const float* skip_mv = (const float*)d_in[2];
    const float* skip_s  = (const float*)d_in[3];
    const float* w_mv    = (const float*)d_in[4];
    const float* w_s2mv  = (const float*)d_in[5];
    const float* w_mv2s  = (const float*)d_in[6];
    const float* w_s2s   = (const float*)d_in[7];
    const float* b_s     = (const float*)d_in[8];

    const int n_parent = in_sizes[0] / 512;   // [Np,32,16]
    const int n_child  = in_sizes[2] / 512;   // [Nc,32,16]
    const int stride   = n_child / n_parent;

    float* out_mv = (float*)d_out;
    float* out_s  = out_mv + (size_t)n_child * 512;

    const int blocks = (n_parent + P_BLK - 1) / P_BLK;
    equi_unpool_v8<<<blocks, TPB, 0, stream>>>(
        x_mv, x_s, skip_mv, skip_s, w_mv, w_s2mv, w_mv2s, w_s2s, b_s,
        out_mv, out_s, n_parent, stride);
}

// Round 9
// 193.263 us; speedup vs baseline: 2.4320x; 2.4320x over previous
//
#include <hip/hip_runtime.h>

typedef __attribute__((ext_vector_type(8))) short bf16x8;
typedef __attribute__((ext_vector_type(4))) float f32x4;

#define THR 256
#define PBLK 32

__device__ __forceinline__ unsigned int bf_rne(float f) {
    unsigned int u = __float_as_uint(f);
    u += 0x7fffu + ((u >> 16) & 1u);
    return u >> 16;
}

#define MFMA(A, B, C) __builtin_amdgcn_mfma_f32_16x16x32_bf16((A), (B), (C), 0, 0, 0)

__global__ __launch_bounds__(THR) void equi_mfma(
    const float* __restrict__ x_mv,    // [Np,32,16]
    const float* __restrict__ x_s,     // [Np,64]
    const float* __restrict__ skip_mv, // [Nc,32,16]
    const float* __restrict__ skip_s,  // [Nc,64]
    const float* __restrict__ w_mv,    // [32,32,9]
    const float* __restrict__ w_s2mv,  // [32,64]
    const float* __restrict__ w_mv2s,  // [64,32]
    const float* __restrict__ w_s2s,   // [64,64]
    const float* __restrict__ b_s,     // [64]
    float* __restrict__ out_mv,        // [Nc,32,16]
    float* __restrict__ out_s,         // [Nc,64]
    int n_parent, int stride)
{
    // Union LDS: staging view (xb 32KB + xsb 4KB) then epilogue view (y 16.9KB + ys 2.1KB)
    __shared__ char smem[36864];
    unsigned short* xb  = (unsigned short*)smem;            // [2ti][16j][16p][4slot][8] bf16
    unsigned short* xsb = (unsigned short*)(smem + 32768);  // [2ti][16p][8slot][8] bf16
    float* y  = (float*)smem;                               // [16j][8p][33] f32
    float* ys = (float*)(smem + 16896);                     // [8p][66] f32

    const int t  = threadIdx.x;
    const int p0 = blockIdx.x * PBLK;

    // ---- stage x_mv -> xb (bf16, i-group XOR swizzle), coalesced dwordx4 reads ----
    {
        const float4* xg = (const float4*)(x_mv + (size_t)p0 * 512);
        #pragma unroll
        for (int k = 0; k < 16; ++k) {
            int id = t + k * THR;                 // f4 index, 0..4095
            float4 v = xg[id];
            int p  = id >> 7;                     // 0..31
            int i  = (id >> 2) & 31;
            int j0 = (id & 3) * 4;
            int ti = p >> 4, pl = p & 15;
            int ig = i >> 3, ie = i & 7;
            int base = ((ti * 16) * 16 + pl) * 32 + ((ig ^ (pl & 3)) * 8) + ie;
            xb[base + (j0 + 0) * 512] = (unsigned short)bf_rne(v.x);
            xb[base + (j0 + 1) * 512] = (unsigned short)bf_rne(v.y);
            xb[base + (j0 + 2) * 512] = (unsigned short)bf_rne(v.z);
            xb[base + (j0 + 3) * 512] = (unsigned short)bf_rne(v.w);
        }
        const float4* xsg = (const float4*)(x_s + (size_t)p0 * 64);
        #pragma unroll
        for (int k = 0; k < 2; ++k) {
            int id = t + k * THR;                 // 0..511
            float4 v = xsg[id];
            int p = id >> 4;
            int s0 = (id & 15) * 4;
            int ti = p >> 4, pl = p & 15;
            int sg = s0 >> 3, se0 = s0 & 7;
            int a = ((ti * 16 + pl) * 8 + (sg ^ (pl & 7))) * 8 + se0;
            xsb[a + 0] = (unsigned short)bf_rne(v.x);
            xsb[a + 1] = (unsigned short)bf_rne(v.y);
            xsb[a + 2] = (unsigned short)bf_rne(v.z);
            xsb[a + 3] = (unsigned short)bf_rne(v.w);
        }
    }

    // ---- build B fragments in registers (global f32 -> bf16; weights are L2-hot) ----
    // B[k][col] layout: lane holds k = (lane>>4)*8+e, col = lane&15.
    const int lane = t & 63;
    const int wid  = t >> 6;
    const int h   = wid & 1;        // o / ch half
    const int jh  = wid >> 1;       // j half (0: j 0-7, 1: j 8-15)
    const int col = lane & 15;
    const int g4  = lane >> 4;
    const int kb  = g4 * 8;

    bf16x8 Bg[3], Bw[2];
    #pragma unroll
    for (int gg = 0; gg < 3; ++gg) {       // grades {2jh, 2jh+1, 2jh+2}
        int b = 2 * jh + gg;
        #pragma unroll
        for (int e = 0; e < 8; ++e)
            Bg[gg][e] = (short)bf_rne(w_mv[(h * 16 + col) * 288 + (kb + e) * 9 + b]);
    }
    #pragma unroll
    for (int ww = 0; ww < 2; ++ww) {       // wedge b {5+2jh, 6+2jh}
        int b = 5 + 2 * jh + ww;
        #pragma unroll
        for (int e = 0; e < 8; ++e)
            Bw[ww][e] = (short)bf_rne(w_mv[(h * 16 + col) * 288 + (kb + e) * 9 + b]);
    }
    bf16x8 Bm2s[2], Bs2mv[2], Bs2s[2][2];
    if (jh == 0) {
        #pragma unroll
        for (int c = 0; c < 2; ++c)
            #pragma unroll
            for (int e = 0; e < 8; ++e)
                Bm2s[c][e] = (short)bf_rne(w_mv2s[((2 * h + c) * 16 + col) * 32 + kb + e]);
        #pragma unroll
        for (int kk = 0; kk < 2; ++kk) {
            #pragma unroll
            for (int e = 0; e < 8; ++e)
                Bs2mv[kk][e] = (short)bf_rne(w_s2mv[(h * 16 + col) * 64 + kk * 32 + kb + e]);
            #pragma unroll
            for (int c = 0; c < 2; ++c)
                #pragma unroll
                for (int e = 0; e < 8; ++e)
                    Bs2s[kk][c][e] = (short)bf_rne(w_s2s[((2 * h + c) * 16 + col) * 64 + kk * 32 + kb + e]);
        }
    }

    __syncthreads();   // xb/xsb ready

    // ---- MFMA phase: D[p][o] tiles; A from xb, B in regs ----
    f32x4 cj[2][8];
    f32x4 cs[2][2];
    #pragma unroll
    for (int ti = 0; ti < 2; ++ti) {
        #pragma unroll
        for (int jj = 0; jj < 8; ++jj) cj[ti][jj] = (f32x4){0.f, 0.f, 0.f, 0.f};
        cs[ti][0] = (f32x4){0.f, 0.f, 0.f, 0.f};
        cs[ti][1] = (f32x4){0.f, 0.f, 0.f, 0.f};
    }
    const int prow = col;               // A row = parent
    const int aslot = (g4 ^ (prow & 3)) * 8;

    if (jh == 0) {
        #pragma unroll
        for (int ti = 0; ti < 2; ++ti) {
            bf16x8 A0;
            #pragma unroll
            for (int jj = 0; jj < 8; ++jj) {
                const unsigned short* ap = &xb[((ti * 16 + jj) * 16 + prow) * 32 + aslot];
                bf16x8 A = *(const bf16x8*)ap;
                // grades for j 0..7: 0,1,1,1,1,2,2,2
                if (jj == 0)      cj[ti][0] = MFMA(A, Bg[0], cj[ti][0]);
                else if (jj < 5)  cj[ti][jj] = MFMA(A, Bg[1], cj[ti][jj]);
                else              cj[ti][jj] = MFMA(A, Bg[2], cj[ti][jj]);
                // wedge: 0->1 (b5), 2->5,3->6,4->7 (b6)
                if (jj == 0) { cj[ti][1] = MFMA(A, Bw[0], cj[ti][1]); A0 = A; }
                else if (jj == 2) cj[ti][5] = MFMA(A, Bw[1], cj[ti][5]);
                else if (jj == 3) cj[ti][6] = MFMA(A, Bw[1], cj[ti][6]);
                else if (jj == 4) cj[ti][7] = MFMA(A, Bw[1], cj[ti][7]);
            }
            cs[ti][0] = MFMA(A0, Bm2s[0], cs[ti][0]);
            cs[ti][1] = MFMA(A0, Bm2s[1], cs[ti][1]);
            #pragma unroll
            for (int kk = 0; kk < 2; ++kk) {
                const unsigned short* sp = &xsb[((ti * 16 + prow) * 8 + ((kk * 4 + g4) ^ (prow & 7))) * 8];
                bf16x8 Axs = *(const bf16x8*)sp;
                cj[ti][0] = MFMA(Axs, Bs2mv[kk], cj[ti][0]);
                cs[ti][0] = MFMA(Axs, Bs2s[kk][0], cs[ti][0]);
                cs[ti][1] = MFMA(Axs, Bs2s[kk][1], cs[ti][1]);
            }
        }
    } else {
        #pragma unroll
        for (int ti = 0; ti < 2; ++ti) {
            #pragma unroll
            for (int jj = 0; jj < 8; ++jj) {
                int j = 8 + jj;
                const unsigned short* ap = &xb[((ti * 16 + j) * 16 + prow) * 32 + aslot];
                bf16x8 A = *(const bf16x8*)ap;
                // grades for j 8..15: 2,2,2,3,3,3,3,4
                if (jj < 3)       cj[ti][jj] = MFMA(A, Bg[0], cj[ti][jj]);
                else if (jj < 7)  cj[ti][jj] = MFMA(A, Bg[1], cj[ti][jj]);
                else              cj[ti][jj] = MFMA(A, Bg[2], cj[ti][jj]);
                // wedge: 8->11, 9->12, 10->13 (b7); 14->15 (b8)
                if (jj == 0)      cj[ti][3] = MFMA(A, Bw[0], cj[ti][3]);
                else if (jj == 1) cj[ti][4] = MFMA(A, Bw[0], cj[ti][4]);
                else if (jj == 2) cj[ti][5] = MFMA(A, Bw[0], cj[ti][5]);
                else if (jj == 6) cj[ti][7] = MFMA(A, Bw[1], cj[ti][7]);
            }
        }
    }

    // ---- epilogue: 4 half-tiles of 8 parents; C->y (LDS) then coalesced stream ----
    #pragma unroll
    for (int hf = 0; hf < 4; ++hf) {
        __syncthreads();   // y region free (xb dead after MFMA / prev stream done)
        const int ti = hf >> 1, plo = (hf & 1) * 8;
        #pragma unroll
        for (int jj = 0; jj < 8; ++jj) {
            int j = jh * 8 + jj;
            #pragma unroll
            for (int r = 0; r < 4; ++r) {
                int p = g4 * 4 + r;
                if (p >= plo && p < plo + 8)
                    y[j * 264 + (p - plo) * 33 + h * 16 + col] = cj[ti][jj][r];
            }
        }
        if (jh == 0) {
            #pragma unroll
            for (int c = 0; c < 2; ++c)
                #pragma unroll
                for (int r = 0; r < 4; ++r) {
                    int p = g4 * 4 + r;
                    if (p >= plo && p < plo + 8)
                        ys[(p - plo) * 66 + (2 * h + c) * 16 + col] = cs[ti][c][r];
                }
        }
        __syncthreads();   // y ready

        const int cbase = (p0 + hf * 8) * stride;
        const float4* sk4 = (const float4*)skip_mv;
        float4* om4 = (float4*)out_mv;
        const int totmv = 8 * stride * 128;
        for (int id = t; id < totmv; id += THR) {
            int child = id >> 7, rem = id & 127;
            int o = rem >> 2, q = rem & 3;
            int ph = child / stride;
            float4 ad;
            ad.x = y[(q * 4 + 0) * 264 + ph * 33 + o];
            ad.y = y[(q * 4 + 1) * 264 + ph * 33 + o];
            ad.z = y[(q * 4 + 2) * 264 + ph * 33 + o];
            ad.w = y[(q * 4 + 3) * 264 + ph * 33 + o];
            size_t gi = (size_t)(cbase + child) * 128 + rem;
            float4 s = sk4[gi];
            om4[gi] = make_float4(s.x + ad.x, s.y + ad.y, s.z + ad.z, s.w + ad.w);
        }
        const float4* sks4 = (const float4*)skip_s;
        float4* os4 = (float4*)out_s;
        const float4* bs4 = (const float4*)b_s;
        const int tots = 8 * stride * 16;
        for (int id = t; id < tots; id += THR) {
            int child = id >> 4, ch4 = id & 15;
            int ph = child / stride;
            float4 ad;
            ad.x = ys[ph * 66 + ch4 * 4 + 0];
            ad.y = ys[ph * 66 + ch4 * 4 + 1];
            ad.z = ys[ph * 66 + ch4 * 4 + 2];
            ad.w = ys[ph * 66 + ch4 * 4 + 3];
            float4 bb = bs4[ch4];
            size_t gi = (size_t)(cbase + child) * 16 + ch4;
            float4 s = sks4[gi];
            os4[gi] = make_float4(s.x + ad.x + bb.x, s.y + ad.y + bb.y,
                                  s.z + ad.z + bb.z, s.w + ad.w + bb.w);
        }
    }
}

// remainder parents (n_parent % 32): slow scalar path, f32, direct global
__global__ __launch_bounds__(256) void equi_tail(
    const float* __restrict__ x_mv, const float* __restrict__ x_s,
    const float* __restrict__ skip_mv, const float* __restrict__ skip_s,
    const float* __restrict__ w_mv, const float* __restrict__ w_s2mv,
    const float* __restrict__ w_mv2s, const float* __restrict__ w_s2s,
    const float* __restrict__ b_s,
    float* __restrict__ out_mv, float* __restrict__ out_s,
    int pstart, int n_parent, int stride)
{
    int idx = blockIdx.x * blockDim.x + threadIdx.x;
    int o = idx & 31, pr = idx >> 5;
    int p = pstart + pr;
    if (p >= n_parent) return;
    float a[16];
    #pragma unroll
    for (int j = 0; j < 16; ++j) a[j] = 0.f;
    float s0 = 0.f, s1 = 0.f;
    const float4* xg = (const float4*)(x_mv + (size_t)p * 512);
    for (int i = 0; i < 32; ++i) {
        float4 X0 = xg[i * 4 + 0], X1 = xg[i * 4 + 1], X2 = xg[i * 4 + 2], X3 = xg[i * 4 + 3];
        const float* wp = &w_mv[o * 288 + i * 9];
        float w0 = wp[0], w1 = wp[1], w2 = wp[2], w3 = wp[3], w4 = wp[4];
        float w5 = wp[5], w6 = wp[6], w7 = wp[7], w8 = wp[8];
        a[0] += X0.x * w0;  a[1] += X0.y * w1 + X0.x * w5;
        a[2] += X0.z * w1;  a[3] += X0.w * w1;  a[4] += X1.x * w1;
        a[5] += X1.y * w2 + X0.z * w6;  a[6] += X1.z * w2 + X0.w * w6;
        a[7] += X1.w * w2 + X1.x * w6;  a[8] += X2.x * w2;
        a[9] += X2.y * w2;  a[10] += X2.z * w2;
        a[11] += X2.w * w3 + X2.x * w7;  a[12] += X3.x * w3 + X2.y * w7;
        a[13] += X3.y * w3 + X2.z * w7;  a[14] += X3.z * w3;
        a[15] += X3.w * w4 + X3.z * w8;
        s0 += X0.x * w_mv2s[o * 32 + i];
        s1 += X0.x * w_mv2s[(o + 32) * 32 + i];
    }
    for (int sc = 0; sc < 64; ++sc) {
        float xv = x_s[(size_t)p * 64 + sc];
        a[0] += xv * w_s2mv[o * 64 + sc];
        s0 += xv * w_s2s[o * 64 + sc];
        s1 += xv * w_s2s[(o + 32) * 64 + sc];
    }
    s0 += b_s[o]; s1 += b_s[o + 32];
    for (int r = 0; r < stride; ++r) {
        size_t c = (size_t)p * stride + r;
        const float4* sk = (const float4*)(skip_mv + c * 512 + o * 16);
        float4* om = (float4*)(out_mv + c * 512 + o * 16);
        float4 k0 = sk[0], k1 = sk[1], k2 = sk[2], k3 = sk[3];
        om[0] = make_float4(k0.x + a[0],  k0.y + a[1],  k0.z + a[2],  k0.w + a[3]);
        om[1] = make_float4(k1.x + a[4],  k1.y + a[5],  k1.z + a[6],  k1.w + a[7]);
        om[2] = make_float4(k2.x + a[8],  k2.y + a[9],  k2.z + a[10], k2.w + a[11]);
        om[3] = make_float4(k3.x + a[12], k3.y + a[13], k3.z + a[14], k3.w + a[15]);
        out_s[c * 64 + o]      = skip_s[c * 64 + o] + s0;
        out_s[c * 64 + o + 32] = skip_s[c * 64 + o + 32] + s1;
    }
}

extern "C" void kernel_launch(void* const* d_in, const int* in_sizes, int n_in,
                              void* d_out, int out_size, void* d_ws, size_t ws_size,
                              hipStream_t stream) {
    const float* x_mv    = (const float*)d_in[0];
    const float* x_s     = (const float*)d_in[1];
    const float* skip_mv = (const float*)d_in[2];
    const float* skip_s  = (const float*)d_in[3];
    const float* w_mv    = (const float*)d_in[4];
    const float* w_s2mv  = (const float*)d_in[5];
    const float* w_mv2s  = (const float*)d_in[6];
    const float* w_s2s   = (const float*)d_in[7];
    const float* b_s     = (const float*)d_in[8];

    const int n_parent = in_sizes[0] / 512;
    const int n_child  = in_sizes[2] / 512;
    const int stride   = n_child / n_parent;

    float* out_mv = (float*)d_out;
    float* out_s  = out_mv + (size_t)n_child * 512;

    const int full = n_parent >> 5;            // blocks of 32 parents
    const int rem  = n_parent & 31;
    if (full > 0)
        equi_mfma<<<full, THR, 0, stream>>>(
            x_mv, x_s, skip_mv, skip_s, w_mv, w_s2mv, w_mv2s, w_s2s, b_s,
            out_mv, out_s, n_parent, stride);
    if (rem > 0) {
        int thr = rem * 32;
        int blk = (thr + 255) / 256;
        equi_tail<<<blk, 256, 0, stream>>>(
            x_mv, x_s, skip_mv, skip_s, w_mv, w_s2mv, w_mv2s, w_s2s, b_s,
            out_mv, out_s, full * 32, n_parent, stride);
    }
}

// Round 10
// 165.868 us; speedup vs baseline: 2.8336x; 1.1652x over previous
//
#include <hip/hip_runtime.h>

typedef __attribute__((ext_vector_type(8))) short bf16x8;
typedef __attribute__((ext_vector_type(4))) float f32x4;

#define THR 256
#define PBLK 32

__device__ __forceinline__ unsigned int bf_rne(float f) {
    unsigned int u = __float_as_uint(f);
    u += 0x7fffu + ((u >> 16) & 1u);
    return u >> 16;
}

#define MFMA(A, B, C) __builtin_amdgcn_mfma_f32_16x16x32_bf16((A), (B), (C), 0, 0, 0)

// xb u16 index: j-stride 520 (coprime-ish to banks), slot XOR'd with ig/pl/jq
#define XB(ti, j, pl, slot) ((ti) * 8320 + (j) * 520 + (pl) * 32 + (slot) * 8)

__global__ __launch_bounds__(THR) void equi_mfma(
    const float* __restrict__ x_mv,    // [Np,32,16]
    const float* __restrict__ x_s,     // [Np,64]
    const float* __restrict__ skip_mv, // [Nc,32,16]
    const float* __restrict__ skip_s,  // [Nc,64]
    const float* __restrict__ w_mv,    // [32,32,9]
    const float* __restrict__ w_s2mv,  // [32,64]
    const float* __restrict__ w_mv2s,  // [64,32]
    const float* __restrict__ w_s2s,   // [64,64]
    const float* __restrict__ b_s,     // [64]
    float* __restrict__ out_mv,        // [Nc,32,16]
    float* __restrict__ out_s,         // [Nc,64]
    int n_parent, int stride)
{
    // Union LDS. staging view: xb 33280 B + xsb 4096 B = 37376.
    // epilogue view: y [16j]x546 f32 (34944 B) + ys [16p]x68 f32 (4352 B) = 39296.
    __shared__ char smem[39296];
    unsigned short* xb  = (unsigned short*)smem;
    unsigned short* xsb = (unsigned short*)(smem + 33280);
    float* y  = (float*)smem;              // Y(j,p,o) = j*546 + p*34 + o
    float* ys = (float*)smem + 8736;       // YS(p,ch) = p*68 + ch (f4-aligned)

    const int t  = threadIdx.x;
    const int p0 = blockIdx.x * PBLK;

    // ---- stage x_mv -> xb (bf16), coalesced dwordx4 reads; 2-way writes ----
    {
        const float4* xg = (const float4*)(x_mv + (size_t)p0 * 512);
        #pragma unroll
        for (int k = 0; k < 16; ++k) {
            int id = t + k * THR;                 // f4 index, 0..4095
            float4 v = xg[id];
            int p  = id >> 7;                     // 0..31
            int i  = (id >> 2) & 31;
            int jq = id & 3;                      // j-quad = j>>2
            int ti = p >> 4, pl = p & 15;
            int ig = i >> 3, ie = i & 7;
            int slot = ig ^ (pl & 3) ^ jq;
            int base = XB(ti, jq * 4, pl, slot) + ie;
            xb[base + 0 * 520] = (unsigned short)bf_rne(v.x);
            xb[base + 1 * 520] = (unsigned short)bf_rne(v.y);
            xb[base + 2 * 520] = (unsigned short)bf_rne(v.z);
            xb[base + 3 * 520] = (unsigned short)bf_rne(v.w);
        }
        const float4* xsg = (const float4*)(x_s + (size_t)p0 * 64);
        #pragma unroll
        for (int k = 0; k < 2; ++k) {
            int id = t + k * THR;                 // 0..511
            float4 v = xsg[id];
            int p = id >> 4;
            int s0 = (id & 15) * 4;
            int ti = p >> 4, pl = p & 15;
            int sg = s0 >> 3, se0 = s0 & 7;
            int a = ((ti * 16 + pl) * 8 + (sg ^ (pl & 7))) * 8 + se0;
            xsb[a + 0] = (unsigned short)bf_rne(v.x);
            xsb[a + 1] = (unsigned short)bf_rne(v.y);
            xsb[a + 2] = (unsigned short)bf_rne(v.z);
            xsb[a + 3] = (unsigned short)bf_rne(v.w);
        }
    }

    // ---- build B fragments in registers (global f32 -> bf16; weights L2-hot) ----
    const int lane = t & 63;
    const int wid  = t >> 6;
    const int h   = wid & 1;        // o / ch half
    const int jh  = wid >> 1;       // j half
    const int col = lane & 15;
    const int g4  = lane >> 4;
    const int kb  = g4 * 8;

    bf16x8 Bg[3], Bw[2];
    #pragma unroll
    for (int gg = 0; gg < 3; ++gg) {       // grades {2jh, 2jh+1, 2jh+2}
        int b = 2 * jh + gg;
        #pragma unroll
        for (int e = 0; e < 8; ++e)
            Bg[gg][e] = (short)bf_rne(w_mv[(h * 16 + col) * 288 + (kb + e) * 9 + b]);
    }
    #pragma unroll
    for (int ww = 0; ww < 2; ++ww) {       // wedge b {5+2jh, 6+2jh}
        int b = 5 + 2 * jh + ww;
        #pragma unroll
        for (int e = 0; e < 8; ++e)
            Bw[ww][e] = (short)bf_rne(w_mv[(h * 16 + col) * 288 + (kb + e) * 9 + b]);
    }
    bf16x8 Bm2s[2], Bs2mv[2], Bs2s[2][2];
    if (jh == 0) {
        #pragma unroll
        for (int c = 0; c < 2; ++c)
            #pragma unroll
            for (int e = 0; e < 8; ++e)
                Bm2s[c][e] = (short)bf_rne(w_mv2s[((2 * h + c) * 16 + col) * 32 + kb + e]);
        #pragma unroll
        for (int kk = 0; kk < 2; ++kk) {
            #pragma unroll
            for (int e = 0; e < 8; ++e)
                Bs2mv[kk][e] = (short)bf_rne(w_s2mv[(h * 16 + col) * 64 + kk * 32 + kb + e]);
            #pragma unroll
            for (int c = 0; c < 2; ++c)
                #pragma unroll
                for (int e = 0; e < 8; ++e)
                    Bs2s[kk][c][e] = (short)bf_rne(w_s2s[((2 * h + c) * 16 + col) * 64 + kk * 32 + kb + e]);
        }
    }

    __syncthreads();   // barrier #1: xb/xsb ready

    // ---- MFMA phase ----
    f32x4 cj[2][8];
    f32x4 cs[2][2];
    #pragma unroll
    for (int ti = 0; ti < 2; ++ti) {
        #pragma unroll
        for (int jj = 0; jj < 8; ++jj) cj[ti][jj] = (f32x4){0.f, 0.f, 0.f, 0.f};
        cs[ti][0] = (f32x4){0.f, 0.f, 0.f, 0.f};
        cs[ti][1] = (f32x4){0.f, 0.f, 0.f, 0.f};
    }
    const int prow = col;

    if (jh == 0) {
        #pragma unroll
        for (int ti = 0; ti < 2; ++ti) {
            bf16x8 A0;
            #pragma unroll
            for (int jj = 0; jj < 8; ++jj) {
                int slot = g4 ^ (prow & 3) ^ (jj >> 2);
                bf16x8 A = *(const bf16x8*)&xb[XB(ti, jj, prow, slot)];
                // grades for j 0..7: 0,1,1,1,1,2,2,2
                if (jj == 0)      cj[ti][0] = MFMA(A, Bg[0], cj[ti][0]);
                else if (jj < 5)  cj[ti][jj] = MFMA(A, Bg[1], cj[ti][jj]);
                else              cj[ti][jj] = MFMA(A, Bg[2], cj[ti][jj]);
                // wedge: 0->1 (b5), 2->5, 3->6, 4->7 (b6)
                if (jj == 0) { cj[ti][1] = MFMA(A, Bw[0], cj[ti][1]); A0 = A; }
                else if (jj == 2) cj[ti][5] = MFMA(A, Bw[1], cj[ti][5]);
                else if (jj == 3) cj[ti][6] = MFMA(A, Bw[1], cj[ti][6]);
                else if (jj == 4) cj[ti][7] = MFMA(A, Bw[1], cj[ti][7]);
            }
            cs[ti][0] = MFMA(A0, Bm2s[0], cs[ti][0]);
            cs[ti][1] = MFMA(A0, Bm2s[1], cs[ti][1]);
            #pragma unroll
            for (int kk = 0; kk < 2; ++kk) {
                const unsigned short* sp = &xsb[((ti * 16 + prow) * 8 + ((kk * 4 + g4) ^ (prow & 7))) * 8];
                bf16x8 Axs = *(const bf16x8*)sp;
                cj[ti][0] = MFMA(Axs, Bs2mv[kk], cj[ti][0]);
                cs[ti][0] = MFMA(Axs, Bs2s[kk][0], cs[ti][0]);
                cs[ti][1] = MFMA(Axs, Bs2s[kk][1], cs[ti][1]);
            }
        }
    } else {
        #pragma unroll
        for (int ti = 0; ti < 2; ++ti) {
            #pragma unroll
            for (int jj = 0; jj < 8; ++jj) {
                int j = 8 + jj;
                int slot = g4 ^ (prow & 3) ^ (j >> 2);
                bf16x8 A = *(const bf16x8*)&xb[XB(ti, j, prow, slot)];
                // grades for j 8..15: 2,2,2,3,3,3,3,4
                if (jj < 3)       cj[ti][jj] = MFMA(A, Bg[0], cj[ti][jj]);
                else if (jj < 7)  cj[ti][jj] = MFMA(A, Bg[1], cj[ti][jj]);
                else              cj[ti][jj] = MFMA(A, Bg[2], cj[ti][jj]);
                // wedge: 8->11, 9->12, 10->13 (b7); 14->15 (b8)
                if (jj == 0)      cj[ti][3] = MFMA(A, Bw[0], cj[ti][3]);
                else if (jj == 1) cj[ti][4] = MFMA(A, Bw[0], cj[ti][4]);
                else if (jj == 2) cj[ti][5] = MFMA(A, Bw[0], cj[ti][5]);
                else if (jj == 6) cj[ti][7] = MFMA(A, Bw[1], cj[ti][7]);
            }
        }
    }

    // ---- epilogue: 2 half-tiles of 16 parents; C -> y (LDS) then coalesced stream ----
    #pragma unroll
    for (int hf = 0; hf < 2; ++hf) {
        __syncthreads();   // xb dead (hf=0) / prev stream y-reads done (hf=1)
        #pragma unroll
        for (int jj = 0; jj < 8; ++jj) {
            int j = jh * 8 + jj;
            #pragma unroll
            for (int r = 0; r < 4; ++r) {
                int p = g4 * 4 + r;
                y[j * 546 + p * 34 + h * 16 + col] = cj[hf][jj][r];
            }
        }
        if (jh == 0) {
            #pragma unroll
            for (int c = 0; c < 2; ++c)
                #pragma unroll
                for (int r = 0; r < 4; ++r) {
                    int p = g4 * 4 + r;
                    ys[p * 68 + (2 * h + c) * 16 + col] = cs[hf][c][r];
                }
        }
        __syncthreads();   // y ready

        const int cbase = (p0 + hf * 16) * stride;
        const float4* sk4 = (const float4*)skip_mv;
        float4* om4 = (float4*)out_mv;
        const float4* sks4 = (const float4*)skip_s;
        float4* os4 = (float4*)out_s;
        const float4* bs4 = (const float4*)b_s;

        if (stride == 2) {
            const int totmv = 16 * 2 * 128;        // 4096 f4
            for (int id = t; id < totmv; id += THR) {
                int child = id >> 7, rem = id & 127;
                int o = rem >> 2, q = rem & 3;
                int ph = child >> 1;
                float4 ad;
                ad.x = y[(q * 4 + 0) * 546 + ph * 34 + o];
                ad.y = y[(q * 4 + 1) * 546 + ph * 34 + o];
                ad.z = y[(q * 4 + 2) * 546 + ph * 34 + o];
                ad.w = y[(q * 4 + 3) * 546 + ph * 34 + o];
                size_t gi = (size_t)(cbase + child) * 128 + rem;
                float4 s = sk4[gi];
                om4[gi] = make_float4(s.x + ad.x, s.y + ad.y, s.z + ad.z, s.w + ad.w);
            }
            const int tots = 16 * 2 * 16;          // 512 f4
            for (int id = t; id < tots; id += THR) {
                int child = id >> 4, ch4 = id & 15;
                int ph = child >> 1;
                float4 ad = *(const float4*)&ys[ph * 68 + ch4 * 4];
                float4 bb = bs4[ch4];
                size_t gi = (size_t)(cbase + child) * 16 + ch4;
                float4 s = sks4[gi];
                os4[gi] = make_float4(s.x + ad.x + bb.x, s.y + ad.y + bb.y,
                                      s.z + ad.z + bb.z, s.w + ad.w + bb.w);
            }
        } else {
            const int totmv = 16 * stride * 128;
            for (int id = t; id < totmv; id += THR) {
                int child = id >> 7, rem = id & 127;
                int o = rem >> 2, q = rem & 3;
                int ph = child / stride;
                float4 ad;
                ad.x = y[(q * 4 + 0) * 546 + ph * 34 + o];
                ad.y = y[(q * 4 + 1) * 546 + ph * 34 + o];
                ad.z = y[(q * 4 + 2) * 546 + ph * 34 + o];
                ad.w = y[(q * 4 + 3) * 546 + ph * 34 + o];
                size_t gi = (size_t)(cbase + child) * 128 + rem;
                float4 s = sk4[gi];
                om4[gi] = make_float4(s.x + ad.x, s.y + ad.y, s.z + ad.z, s.w + ad.w);
            }
            const int tots = 16 * stride * 16;
            for (int id = t; id < tots; id += THR) {
                int child = id >> 4, ch4 = id & 15;
                int ph = child / stride;
                float4 ad = *(const float4*)&ys[ph * 68 + ch4 * 4];
                float4 bb = bs4[ch4];
                size_t gi = (size_t)(cbase + child) * 16 + ch4;
                float4 s = sks4[gi];
                os4[gi] = make_float4(s.x + ad.x + bb.x, s.y + ad.y + bb.y,
                                      s.z + ad.z + bb.z, s.w + ad.w + bb.w);
            }
        }
    }
}

// remainder parents (n_parent % 32): slow scalar path, f32, direct global
__global__ __launch_bounds__(256) void equi_tail(
    const float* __restrict__ x_mv, const float* __restrict__ x_s,
    const float* __restrict__ skip_mv, const float* __restrict__ skip_s,
    const float* __restrict__ w_mv, const float* __restrict__ w_s2mv,
    const float* __restrict__ w_mv2s, const float* __restrict__ w_s2s,
    const float* __restrict__ b_s,
    float* __restrict__ out_mv, float* __restrict__ out_s,
    int pstart, int n_parent, int stride)
{
    int idx = blockIdx.x * blockDim.x + threadIdx.x;
    int o = idx & 31, pr = idx >> 5;
    int p = pstart + pr;
    if (p >= n_parent) return;
    float a[16];
    #pragma unroll
    for (int j = 0; j < 16; ++j) a[j] = 0.f;
    float s0 = 0.f, s1 = 0.f;
    const float4* xg = (const float4*)(x_mv + (size_t)p * 512);
    for (int i = 0; i < 32; ++i) {
        float4 X0 = xg[i * 4 + 0], X1 = xg[i * 4 + 1], X2 = xg[i * 4 + 2], X3 = xg[i * 4 + 3];
        const float* wp = &w_mv[o * 288 + i * 9];
        float w0 = wp[0], w1 = wp[1], w2 = wp[2], w3 = wp[3], w4 = wp[4];
        float w5 = wp[5], w6 = wp[6], w7 = wp[7], w8 = wp[8];
        a[0] += X0.x * w0;  a[1] += X0.y * w1 + X0.x * w5;
        a[2] += X0.z * w1;  a[3] += X0.w * w1;  a[4] += X1.x * w1;
        a[5] += X1.y * w2 + X0.z * w6;  a[6] += X1.z * w2 + X0.w * w6;
        a[7] += X1.w * w2 + X1.x * w6;  a[8] += X2.x * w2;
        a[9] += X2.y * w2;  a[10] += X2.z * w2;
        a[11] += X2.w * w3 + X2.x * w7;  a[12] += X3.x * w3 + X2.y * w7;
        a[13] += X3.y * w3 + X2.z * w7;  a[14] += X3.z * w3;
        a[15] += X3.w * w4 + X3.z * w8;
        s0 += X0.x * w_mv2s[o * 32 + i];
        s1 += X0.x * w_mv2s[(o + 32) * 32 + i];
    }
    for (int sc = 0; sc < 64; ++sc) {
        float xv = x_s[(size_t)p * 64 + sc];
        a[0] += xv * w_s2mv[o * 64 + sc];
        s0 += xv * w_s2s[o * 64 + sc];
        s1 += xv * w_s2s[(o + 32) * 64 + sc];
    }
    s0 += b_s[o]; s1 += b_s[o + 32];
    for (int r = 0; r < stride; ++r) {
        size_t c = (size_t)p * stride + r;
        const float4* sk = (const float4*)(skip_mv + c * 512 + o * 16);
        float4* om = (float4*)(out_mv + c * 512 + o * 16);
        float4 k0 = sk[0], k1 = sk[1], k2 = sk[2], k3 = sk[3];
        om[0] = make_float4(k0.x + a[0],  k0.y + a[1],  k0.z + a[2],  k0.w + a[3]);
        om[1] = make_float4(k1.x + a[4],  k1.y + a[5],  k1.z + a[6],  k1.w + a[7]);
        om[2] = make_float4(k2.x + a[8],  k2.y + a[9],  k2.z + a[10], k2.w + a[11]);
        om[3] = make_float4(k3.x + a[12], k3.y + a[13], k3.z + a[14], k3.w + a[15]);
        out_s[c * 64 + o]      = skip_s[c * 64 + o] + s0;
        out_s[c * 64 + o + 32] = skip_s[c * 64 + o + 32] + s1;
    }
}

extern "C" void kernel_launch(void* const* d_in, const int* in_sizes, int n_in,
                              void* d_out, int out_size, void* d_ws, size_t ws_size,
                              hipStream_t stream) {
    const float* x_mv    = (const float*)d_in[0];
    const float* x_s     = (const float*)d_in[1];
    const float* skip_mv = (const float*)d_in[2];
    const float* skip_s  = (const float*)d_in[3];
    const float* w_mv    = (const float*)d_in[4];
    const float* w_s2mv  = (const float*)d_in[5];
    const float* w_mv2s  = (const float*)d_in[6];
    const float* w_s2s   = (const float*)d_in[7];
    const float* b_s     = (const float*)d_in[8];

    const int n_parent = in_sizes[0] / 512;
    const int n_child  = in_sizes[2] / 512;
    const int stride   = n_child / n_parent;

    float* out_mv = (float*)d_out;
    float* out_s  = out_mv + (size_t)n_child * 512;

    const int full = n_parent >> 5;
    const int rem  = n_parent & 31;
    if (full > 0)
        equi_mfma<<<full, THR, 0, stream>>>(
            x_mv, x_s, skip_mv, skip_s, w_mv, w_s2mv, w_mv2s, w_s2s, b_s,
            out_mv, out_s, n_parent, stride);
    if (rem > 0) {
        int thr = rem * 32;
        int blk = (thr + 255) / 256;
        equi_tail<<<blk, 256, 0, stream>>>(
            x_mv, x_s, skip_mv, skip_s, w_mv, w_s2mv, w_mv2s, w_s2s, b_s,
            out_mv, out_s, full * 32, n_parent, stride);
    }
}

// Round 12
// 163.472 us; speedup vs baseline: 2.8752x; 1.0147x over previous
//
#include <hip/hip_runtime.h>

typedef __attribute__((ext_vector_type(8))) short bf16x8;
typedef __attribute__((ext_vector_type(4))) float f32x4;

#define THR 256
#define PBLK 32

__device__ __forceinline__ unsigned int bf_rne(float f) {
    unsigned int u = __float_as_uint(f);
    u += 0x7fffu + ((u >> 16) & 1u);
    return u >> 16;
}

#define MFMA(A, B, C) __builtin_amdgcn_mfma_f32_16x16x32_bf16((A), (B), (C), 0, 0, 0)

// xb u16 index: j-stride 520, slot XOR'd with ig/pl/jq (A-reads/writes ~2-way)
#define XB(ti, j, pl, slot) ((ti) * 8320 + (j) * 520 + (pl) * 32 + (slot) * 8)
#define YPS 520   // y p-stride (f32): 32 o x 16 j + 8 pad  (o reaches 31!)
#define YSS 68    // ys p-stride (f32): 64 ch + 4 pad

__global__ __launch_bounds__(THR) void equi_mfma(
    const float* __restrict__ x_mv,    // [Np,32,16]
    const float* __restrict__ x_s,     // [Np,64]
    const float* __restrict__ skip_mv, // [Nc,32,16]
    const float* __restrict__ skip_s,  // [Nc,64]
    const float* __restrict__ w_mv,    // [32,32,9]
    const float* __restrict__ w_s2mv,  // [32,64]
    const float* __restrict__ w_mv2s,  // [64,32]
    const float* __restrict__ w_s2s,   // [64,64]
    const float* __restrict__ b_s,     // [64]
    float* __restrict__ out_mv,        // [Nc,32,16]
    float* __restrict__ out_s,         // [Nc,64]
    int n_parent, int stride)
{
    // Union LDS. staging view: xb 33280 B + xsb 4096 B = 37376 B.
    // epilogue view: y 16p*520*4 = 33280 B (over xb) + ys 16p*68*4 = 4352 B = 37632 B.
    __shared__ char smem[37632];
    unsigned short* xb  = (unsigned short*)smem;
    unsigned short* xsb = (unsigned short*)(smem + 33280);
    float* y  = (float*)smem;                       // Y(p,o,quad',m) = p*520 + o*16 + quad'*4 + m
    float* ys = (float*)(smem + 33280);             // YS(p,ch) = p*68 + ch

    const int t  = threadIdx.x;
    const int p0 = blockIdx.x * PBLK;

    // ---- stage x_mv -> xb: thread = (p, ig2, jq); 16 f4 loads -> 8 ds_write_b128 ----
    {
        const int p   = t >> 3;
        const int ig2 = (t >> 2) & 1;
        const int jq  = t & 3;
        const int ti  = p >> 4, pl = p & 15;
        const float4* xg = (const float4*)(x_mv + (size_t)p0 * 512);
        const int base = p * 128 + ig2 * 64 + jq;
        bf16x8 acc[4][2];     // [jo][igl]
        #pragma unroll
        for (int s = 0; s < 16; ++s) {
            float4 v = xg[base + s * 4];
            int igl = s >> 3, e = s & 7;
            acc[0][igl][e] = (short)bf_rne(v.x);
            acc[1][igl][e] = (short)bf_rne(v.y);
            acc[2][igl][e] = (short)bf_rne(v.z);
            acc[3][igl][e] = (short)bf_rne(v.w);
        }
        #pragma unroll
        for (int jo = 0; jo < 4; ++jo)
            #pragma unroll
            for (int igl = 0; igl < 2; ++igl) {
                int ig = ig2 * 2 + igl;
                int slot = ig ^ (pl & 3) ^ jq;
                *(bf16x8*)&xb[XB(ti, jq * 4 + jo, pl, slot)] = acc[jo][igl];
            }
        // x_s -> xsb: thread = (p, q); 2 f4 loads -> 1 ds_write_b128
        const int q = t & 7;
        const int ps = t >> 3;
        const int tis = ps >> 4, pls = ps & 15;
        const float4* xsg = (const float4*)(x_s + (size_t)p0 * 64);
        float4 v0 = xsg[ps * 16 + q * 2 + 0];
        float4 v1 = xsg[ps * 16 + q * 2 + 1];
        bf16x8 sv;
        sv[0] = (short)bf_rne(v0.x); sv[1] = (short)bf_rne(v0.y);
        sv[2] = (short)bf_rne(v0.z); sv[3] = (short)bf_rne(v0.w);
        sv[4] = (short)bf_rne(v1.x); sv[5] = (short)bf_rne(v1.y);
        sv[6] = (short)bf_rne(v1.z); sv[7] = (short)bf_rne(v1.w);
        *(bf16x8*)&xsb[((tis * 16 + pls) * 8 + (q ^ (pls & 7))) * 8] = sv;
    }

    // ---- build B fragments in registers (global f32 -> bf16; weights L2-hot) ----
    const int lane = t & 63;
    const int wid  = t >> 6;
    const int h   = wid & 1;        // o / ch half
    const int jh  = wid >> 1;       // j half
    const int col = lane & 15;
    const int g4  = lane >> 4;
    const int kb  = g4 * 8;
    const int oo  = h * 16 + col;   // global o this lane owns in B/C

    bf16x8 Bg[3], Bw[2];
    #pragma unroll
    for (int gg = 0; gg < 3; ++gg) {
        int b = 2 * jh + gg;
        #pragma unroll
        for (int e = 0; e < 8; ++e)
            Bg[gg][e] = (short)bf_rne(w_mv[oo * 288 + (kb + e) * 9 + b]);
    }
    #pragma unroll
    for (int ww = 0; ww < 2; ++ww) {
        int b = 5 + 2 * jh + ww;
        #pragma unroll
        for (int e = 0; e < 8; ++e)
            Bw[ww][e] = (short)bf_rne(w_mv[oo * 288 + (kb + e) * 9 + b]);
    }
    bf16x8 Bm2s[2], Bs2mv[2], Bs2s[2][2];
    if (jh == 0) {
        #pragma unroll
        for (int c = 0; c < 2; ++c)
            #pragma unroll
            for (int e = 0; e < 8; ++e)
                Bm2s[c][e] = (short)bf_rne(w_mv2s[((2 * h + c) * 16 + col) * 32 + kb + e]);
        #pragma unroll
        for (int kk = 0; kk < 2; ++kk) {
            #pragma unroll
            for (int e = 0; e < 8; ++e)
                Bs2mv[kk][e] = (short)bf_rne(w_s2mv[oo * 64 + kk * 32 + kb + e]);
            #pragma unroll
            for (int c = 0; c < 2; ++c)
                #pragma unroll
                for (int e = 0; e < 8; ++e)
                    Bs2s[kk][c][e] = (short)bf_rne(w_s2s[((2 * h + c) * 16 + col) * 64 + kk * 32 + kb + e]);
        }
    }

    __syncthreads();   // barrier #1: xb/xsb ready

    // ---- MFMA phase ----
    f32x4 cj[2][8];
    f32x4 cs[2][2];
    #pragma unroll
    for (int ti = 0; ti < 2; ++ti) {
        #pragma unroll
        for (int jj = 0; jj < 8; ++jj) cj[ti][jj] = (f32x4){0.f, 0.f, 0.f, 0.f};
        cs[ti][0] = (f32x4){0.f, 0.f, 0.f, 0.f};
        cs[ti][1] = (f32x4){0.f, 0.f, 0.f, 0.f};
    }
    const int prow = col;

    if (jh == 0) {
        #pragma unroll
        for (int ti = 0; ti < 2; ++ti) {
            bf16x8 A0;
            #pragma unroll
            for (int jj = 0; jj < 8; ++jj) {
                int slot = g4 ^ (prow & 3) ^ (jj >> 2);
                bf16x8 A = *(const bf16x8*)&xb[XB(ti, jj, prow, slot)];
                if (jj == 0)      cj[ti][0] = MFMA(A, Bg[0], cj[ti][0]);
                else if (jj < 5)  cj[ti][jj] = MFMA(A, Bg[1], cj[ti][jj]);
                else              cj[ti][jj] = MFMA(A, Bg[2], cj[ti][jj]);
                if (jj == 0) { cj[ti][1] = MFMA(A, Bw[0], cj[ti][1]); A0 = A; }
                else if (jj == 2) cj[ti][5] = MFMA(A, Bw[1], cj[ti][5]);
                else if (jj == 3) cj[ti][6] = MFMA(A, Bw[1], cj[ti][6]);
                else if (jj == 4) cj[ti][7] = MFMA(A, Bw[1], cj[ti][7]);
            }
            cs[ti][0] = MFMA(A0, Bm2s[0], cs[ti][0]);
            cs[ti][1] = MFMA(A0, Bm2s[1], cs[ti][1]);
            #pragma unroll
            for (int kk = 0; kk < 2; ++kk) {
                const unsigned short* sp = &xsb[((ti * 16 + prow) * 8 + ((kk * 4 + g4) ^ (prow & 7))) * 8];
                bf16x8 Axs = *(const bf16x8*)sp;
                cj[ti][0] = MFMA(Axs, Bs2mv[kk], cj[ti][0]);
                cs[ti][0] = MFMA(Axs, Bs2s[kk][0], cs[ti][0]);
                cs[ti][1] = MFMA(Axs, Bs2s[kk][1], cs[ti][1]);
            }
        }
    } else {
        #pragma unroll
        for (int ti = 0; ti < 2; ++ti) {
            #pragma unroll
            for (int jj = 0; jj < 8; ++jj) {
                int j = 8 + jj;
                int slot = g4 ^ (prow & 3) ^ (j >> 2);
                bf16x8 A = *(const bf16x8*)&xb[XB(ti, j, prow, slot)];
                if (jj < 3)       cj[ti][jj] = MFMA(A, Bg[0], cj[ti][jj]);
                else if (jj < 7)  cj[ti][jj] = MFMA(A, Bg[1], cj[ti][jj]);
                else              cj[ti][jj] = MFMA(A, Bg[2], cj[ti][jj]);
                if (jj == 0)      cj[ti][3] = MFMA(A, Bw[0], cj[ti][3]);
                else if (jj == 1) cj[ti][4] = MFMA(A, Bw[0], cj[ti][4]);
                else if (jj == 2) cj[ti][5] = MFMA(A, Bw[0], cj[ti][5]);
                else if (jj == 6) cj[ti][7] = MFMA(A, Bw[1], cj[ti][7]);
            }
        }
    }

    // ---- epilogue: 2 half-tiles of 16 parents; vectorized C->y then coalesced stream ----
    #pragma unroll
    for (int hf = 0; hf < 2; ++hf) {
        __syncthreads();   // xb/xsb dead (hf=0) / prev y-reads done (hf=1)
        #pragma unroll
        for (int r = 0; r < 4; ++r) {
            int p = g4 * 4 + r;
            #pragma unroll
            for (int q4 = 0; q4 < 2; ++q4) {
                int jqg  = jh * 2 + q4;                 // global j-quad
                int quad = jqg ^ (oo & 3) ^ g4;         // g4 == p>>2
                float4 w;
                w.x = cj[hf][q4 * 4 + 0][r];
                w.y = cj[hf][q4 * 4 + 1][r];
                w.z = cj[hf][q4 * 4 + 2][r];
                w.w = cj[hf][q4 * 4 + 3][r];
                *(float4*)&y[p * YPS + oo * 16 + quad * 4] = w;
            }
        }
        if (jh == 0) {
            #pragma unroll
            for (int c = 0; c < 2; ++c)
                #pragma unroll
                for (int r = 0; r < 4; ++r)
                    ys[(g4 * 4 + r) * YSS + (2 * h + c) * 16 + col] = cs[hf][c][r];
        }
        __syncthreads();   // y ready

        const int cbase = (p0 + hf * 16) * stride;
        const float4* sk4 = (const float4*)skip_mv;
        float4* om4 = (float4*)out_mv;
        const float4* sks4 = (const float4*)skip_s;
        float4* os4 = (float4*)out_s;
        const float4* bs4 = (const float4*)b_s;

        if (stride == 2) {
            const int totmv = 16 * 2 * 128;        // 4096 f4
            for (int id = t; id < totmv; id += THR) {
                int child = id >> 7, rem = id & 127;
                int o = rem >> 2, q = rem & 3;
                int ph = child >> 1;
                int quad = q ^ (o & 3) ^ (ph >> 2);
                float4 ad = *(const float4*)&y[ph * YPS + o * 16 + quad * 4];
                size_t gi = (size_t)(cbase + child) * 128 + rem;
                float4 s = sk4[gi];
                om4[gi] = make_float4(s.x + ad.x, s.y + ad.y, s.z + ad.z, s.w + ad.w);
            }
            const int tots = 16 * 2 * 16;          // 512 f4
            for (int id = t; id < tots; id += THR) {
                int child = id >> 4, ch4 = id & 15;
                int ph = child >> 1;
                float4 ad = *(const float4*)&ys[ph * YSS + ch4 * 4];
                float4 bb = bs4[ch4];
                size_t gi = (size_t)(cbase + child) * 16 + ch4;
                float4 s = sks4[gi];
                os4[gi] = make_float4(s.x + ad.x + bb.x, s.y + ad.y + bb.y,
                                      s.z + ad.z + bb.z, s.w + ad.w + bb.w);
            }
        } else {
            const int totmv = 16 * stride * 128;
            for (int id = t; id < totmv; id += THR) {
                int child = id >> 7, rem = id & 127;
                int o = rem >> 2, q = rem & 3;
                int ph = child / stride;
                int quad = q ^ (o & 3) ^ (ph >> 2);
                float4 ad = *(const float4*)&y[ph * YPS + o * 16 + quad * 4];
                size_t gi = (size_t)(cbase + child) * 128 + rem;
                float4 s = sk4[gi];
                om4[gi] = make_float4(s.x + ad.x, s.y + ad.y, s.z + ad.z, s.w + ad.w);
            }
            const int tots = 16 * stride * 16;
            for (int id = t; id < tots; id += THR) {
                int child = id >> 4, ch4 = id & 15;
                int ph = child / stride;
                float4 ad = *(const float4*)&ys[ph * YSS + ch4 * 4];
                float4 bb = bs4[ch4];
                size_t gi = (size_t)(cbase + child) * 16 + ch4;
                float4 s = sks4[gi];
                os4[gi] = make_float4(s.x + ad.x + bb.x, s.y + ad.y + bb.y,
                                      s.z + ad.z + bb.z, s.w + ad.w + bb.w);
            }
        }
    }
}

// remainder parents (n_parent % 32): slow scalar path, f32, direct global
__global__ __launch_bounds__(256) void equi_tail(
    const float* __restrict__ x_mv, const float* __restrict__ x_s,
    const float* __restrict__ skip_mv, const float* __restrict__ skip_s,
    const float* __restrict__ w_mv, const float* __restrict__ w_s2mv,
    const float* __restrict__ w_mv2s, const float* __restrict__ w_s2s,
    const float* __restrict__ b_s,
    float* __restrict__ out_mv, float* __restrict__ out_s,
    int pstart, int n_parent, int stride)
{
    int idx = blockIdx.x * blockDim.x + threadIdx.x;
    int o = idx & 31, pr = idx >> 5;
    int p = pstart + pr;
    if (p >= n_parent) return;
    float a[16];
    #pragma unroll
    for (int j = 0; j < 16; ++j) a[j] = 0.f;
    float s0 = 0.f, s1 = 0.f;
    const float4* xg = (const float4*)(x_mv + (size_t)p * 512);
    for (int i = 0; i < 32; ++i) {
        float4 X0 = xg[i * 4 + 0], X1 = xg[i * 4 + 1], X2 = xg[i * 4 + 2], X3 = xg[i * 4 + 3];
        const float* wp = &w_mv[o * 288 + i * 9];
        float w0 = wp[0], w1 = wp[1], w2 = wp[2], w3 = wp[3], w4 = wp[4];
        float w5 = wp[5], w6 = wp[6], w7 = wp[7], w8 = wp[8];
        a[0] += X0.x * w0;  a[1] += X0.y * w1 + X0.x * w5;
        a[2] += X0.z * w1;  a[3] += X0.w * w1;  a[4] += X1.x * w1;
        a[5] += X1.y * w2 + X0.z * w6;  a[6] += X1.z * w2 + X0.w * w6;
        a[7] += X1.w * w2 + X1.x * w6;  a[8] += X2.x * w2;
        a[9] += X2.y * w2;  a[10] += X2.z * w2;
        a[11] += X2.w * w3 + X2.x * w7;  a[12] += X3.x * w3 + X2.y * w7;
        a[13] += X3.y * w3 + X2.z * w7;  a[14] += X3.z * w3;
        a[15] += X3.w * w4 + X3.z * w8;
        s0 += X0.x * w_mv2s[o * 32 + i];
        s1 += X0.x * w_mv2s[(o + 32) * 32 + i];
    }
    for (int sc = 0; sc < 64; ++sc) {
        float xv = x_s[(size_t)p * 64 + sc];
        a[0] += xv * w_s2mv[o * 64 + sc];
        s0 += xv * w_s2s[o * 64 + sc];
        s1 += xv * w_s2s[(o + 32) * 64 + sc];
    }
    s0 += b_s[o]; s1 += b_s[o + 32];
    for (int r = 0; r < stride; ++r) {
        size_t c = (size_t)p * stride + r;
        const float4* sk = (const float4*)(skip_mv + c * 512 + o * 16);
        float4* om = (float4*)(out_mv + c * 512 + o * 16);
        float4 k0 = sk[0], k1 = sk[1], k2 = sk[2], k3 = sk[3];
        om[0] = make_float4(k0.x + a[0],  k0.y + a[1],  k0.z + a[2],  k0.w + a[3]);
        om[1] = make_float4(k1.x + a[4],  k1.y + a[5],  k1.z + a[6],  k1.w + a[7]);
        om[2] = make_float4(k2.x + a[8],  k2.y + a[9],  k2.z + a[10], k2.w + a[11]);
        om[3] = make_float4(k3.x + a[12], k3.y + a[13], k3.z + a[14], k3.w + a[15]);
        out_s[c * 64 + o]      = skip_s[c * 64 + o] + s0;
        out_s[c * 64 + o + 32] = skip_s[c * 64 + o + 32] + s1;
    }
}

extern "C" void kernel_launch(void* const* d_in, const int* in_sizes, int n_in,
                              void* d_out, int out_size, void* d_ws, size_t ws_size,
                              hipStream_t stream) {
    const float* x_mv    = (const float*)d_in[0];
    const float* x_s     = (const float*)d_in[1];
    const float* skip_mv = (const float*)d_in[2];
    const float* skip_s  = (const float*)d_in[3];
    const float* w_mv    = (const float*)d_in[4];
    const float* w_s2mv  = (const float*)d_in[5];
    const float* w_mv2s  = (const float*)d_in[6];
    const float* w_s2s   = (const float*)d_in[7];
    const float* b_s     = (const float*)d_in[8];

    const int n_parent = in_sizes[0] / 512;
    const int n_child  = in_sizes[2] / 512;
    const int stride   = n_child / n_parent;

    float* out_mv = (float*)d_out;
    float* out_s  = out_mv + (size_t)n_child * 512;

    const int full = n_parent >> 5;
    const int rem  = n_parent & 31;
    if (full > 0)
        equi_mfma<<<full, THR, 0, stream>>>(
            x_mv, x_s, skip_mv, skip_s, w_mv, w_s2mv, w_mv2s, w_s2s, b_s,
            out_mv, out_s, n_parent, stride);
    if (rem > 0) {
        int thr = rem * 32;
        int blk = (thr + 255) / 256;
        equi_tail<<<blk, 256, 0, stream>>>(
            x_mv, x_s, skip_mv, skip_s, w_mv, w_s2mv, w_mv2s, w_s2s, b_s,
            out_mv, out_s, full * 32, n_parent, stride);
    }
}